// Round 9
// baseline (707.885 us; speedup 1.0000x reference)
//
#include <hip/hip_runtime.h>
#include <cstdint>
#include <cstddef>

#define NU 100000
#define NI 50000
#define NTOT 150000
#define EDIM 64
#define NE 1000000
#define NLAYERS 3
#define SCAN_CHUNK 1024
#define NBLK ((NTOT + SCAN_CHUNK - 1) / SCAN_CHUNK)   // 147
#define FILL_PASSES 8
#define FILL_RANGE (NTOT / FILL_PASSES)               // 18750
#define NTILES (NTOT / 16)                            // 9375

// byte-packed degree histogram: 4 nodes/word, 32768 nodes per 32KB block.
#define HB_BYTES 32768
#define HB_WORDS (HB_BYTES / 4)
#define NSLICE 128
#define ESLICE ((NE + NSLICE - 1) / NSLICE)           // 7813
#define NRANGE_U 4
#define NRANGE_I 2
#define NRANGE (NRANGE_U + NRANGE_I)
#define NWORDS (NTOT / 4)                             // 37500

typedef __attribute__((ext_vector_type(8))) short short8;   // 8 bf16 (4 VGPRs)
typedef __attribute__((ext_vector_type(4))) float floatx4;  // 4 fp32 acc

// ---------------- bf16 helpers (raw-bit, RNE) ----------------
__device__ inline unsigned short f2bf(float f) {
    unsigned u = __float_as_uint(f);
    u += 0x7fffu + ((u >> 16) & 1u);
    return (unsigned short)(u >> 16);
}
__device__ inline unsigned pack_bf2(float a, float b) {
    unsigned ua = __float_as_uint(a); ua += 0x7fffu + ((ua >> 16) & 1u);
    unsigned ub = __float_as_uint(b); ub += 0x7fffu + ((ub >> 16) & 1u);
    return (ua >> 16) | (ub & 0xffff0000u);
}
__device__ inline float bf_lo(unsigned u) { return __uint_as_float(u << 16); }
__device__ inline float bf_hi(unsigned u) { return __uint_as_float(u & 0xffff0000u); }

// ---------------- degree histogram, byte-packed LDS ----------------
__global__ __launch_bounds__(256) void k_hist(const int* __restrict__ eu,
                                              const int* __restrict__ ei,
                                              unsigned* __restrict__ partial) {
    __shared__ unsigned h[HB_WORDS];
    int r = blockIdx.x / NSLICE;
    int s = blockIdx.x % NSLICE;
    const int* arr;
    int base, gbyte, lim;
    if (r < NRANGE_U) {
        arr = eu; base = r * HB_BYTES; gbyte = base;
        lim = min(HB_BYTES, NU - base);
    } else {
        arr = ei; base = (r - NRANGE_U) * HB_BYTES; gbyte = NU + base;
        lim = min(HB_BYTES, NI - base);
    }
    for (int i = threadIdx.x; i < HB_WORDS; i += 256) h[i] = 0;
    __syncthreads();
    const int e0 = s * ESLICE, e1 = min(NE, e0 + ESLICE);
    for (int e = e0 + threadIdx.x; e < e1; e += 256) {
        unsigned local = (unsigned)(arr[e] - base);
        if (local < (unsigned)HB_BYTES)
            atomicAdd(&h[local >> 2], 1u << ((local & 3u) * 8u));
    }
    __syncthreads();
    unsigned* dst = partial + (size_t)s * NWORDS + (gbyte >> 2);
    int lw = lim >> 2;
    for (int i = threadIdx.x; i < lw; i += 256) dst[i] = h[i];
}

__global__ void k_merge(const unsigned* __restrict__ partial, int* __restrict__ deg,
                        float* __restrict__ isq, float* __restrict__ inv) {
    int n = blockIdx.x * blockDim.x + threadIdx.x;
    if (n >= NWORDS) return;
    unsigned se = 0, so = 0;
    for (int s = 0; s < NSLICE; ++s) {
        unsigned v = partial[(size_t)s * NWORDS + n];
        se += v & 0x00ff00ffu;
        so += (v >> 8) & 0x00ff00ffu;
    }
    int d[4];
    d[0] = se & 0xffff; d[1] = so & 0xffff;
    d[2] = se >> 16;    d[3] = so >> 16;
    ((int4*)deg)[n] = make_int4(d[0], d[1], d[2], d[3]);
    float4 q, iv;
    float* qp = &q.x; float* ip = &iv.x;
#pragma unroll
    for (int j = 0; j < 4; ++j) {
        float df = (float)d[j];
        qp[j] = d[j] > 0 ? 1.0f / sqrtf(df) : 0.f;
        ip[j] = d[j] > 0 ? 1.0f / df : 0.f;
    }
    ((float4*)isq)[n] = q;
    ((float4*)inv)[n] = iv;
}

// ---------------- scan kernels ----------------

__global__ void k_blocksum(const int* __restrict__ deg, int* __restrict__ partials) {
    __shared__ int sm[256];
    int b = blockIdx.x, t = threadIdx.x;
    int base = b * SCAN_CHUNK + t * 4;
    int s = 0;
#pragma unroll
    for (int j = 0; j < 4; ++j) {
        int idx = base + j;
        if (idx < NTOT) s += deg[idx];
    }
    sm[t] = s;
    __syncthreads();
    for (int off = 128; off > 0; off >>= 1) {
        if (t < off) sm[t] += sm[t + off];
        __syncthreads();
    }
    if (t == 0) partials[b] = sm[0];
}

__global__ void k_scanpartials(int* __restrict__ partials, int nblk) {
    __shared__ int sm[256];
    int t = threadIdx.x;
    int v = (t < nblk) ? partials[t] : 0;
    sm[t] = v;
    __syncthreads();
    for (int off = 1; off < 256; off <<= 1) {
        int tmp = (t >= off) ? sm[t - off] : 0;
        __syncthreads();
        sm[t] += tmp;
        __syncthreads();
    }
    if (t < nblk) partials[t] = sm[t] - v;   // exclusive
}

__global__ void k_scanfinal(const int* __restrict__ deg, const int* __restrict__ partials,
                            int* __restrict__ start, int* __restrict__ cursor) {
    __shared__ int sm[256];
    int b = blockIdx.x, t = threadIdx.x;
    int base = b * SCAN_CHUNK + t * 4;
    int v[4];
    int s = 0;
#pragma unroll
    for (int j = 0; j < 4; ++j) {
        int idx = base + j;
        v[j] = (idx < NTOT) ? deg[idx] : 0;
        s += v[j];
    }
    sm[t] = s;
    __syncthreads();
    for (int off = 1; off < 256; off <<= 1) {
        int tmp = (t >= off) ? sm[t - off] : 0;
        __syncthreads();
        sm[t] += tmp;
        __syncthreads();
    }
    int excl = partials[b] + sm[t] - s;
#pragma unroll
    for (int j = 0; j < 4; ++j) {
        int idx = base + j;
        if (idx < NTOT) {
            start[idx] = excl;
            cursor[idx] = excl;
            excl += v[j];
        }
    }
}

// range-filtered CSR fill
__global__ void k_fill_pass(const int* __restrict__ eu, const int* __restrict__ ei,
                            int* __restrict__ cursor, int* __restrict__ csr,
                            int lo, int hi) {
    int e = blockIdx.x * blockDim.x + threadIdx.x;
    if (e < NE) {
        int u = eu[e];
        int v = NU + ei[e];
        if (u >= lo && u < hi) {
            int p = atomicAdd(&cursor[u], 1);
            csr[p] = v;
        }
        if (v >= lo && v < hi) {
            int p = atomicAdd(&cursor[v], 1);
            csr[p] = u;
        }
    }
}

// W f32 -> bf16 pre-conversion (both matrices, all layers)
__global__ void k_prepw(const float* __restrict__ Wg, const float* __restrict__ Wb,
                        unsigned short* __restrict__ wgb, unsigned short* __restrict__ wbb) {
    int i = blockIdx.x * blockDim.x + threadIdx.x;   // per 4 elems
    const int n4 = NLAYERS * 4096 / 4;
    if (i < n4) {
        float4 g4 = ((const float4*)Wg)[i];
        float4 b4 = ((const float4*)Wb)[i];
        uint2 g, b;
        g.x = pack_bf2(g4.x, g4.y); g.y = pack_bf2(g4.z, g4.w);
        b.x = pack_bf2(b4.x, b4.y); b.y = pack_bf2(b4.z, b4.w);
        ((uint2*)wgb)[i] = g;
        ((uint2*)wbb)[i] = b;
    }
}

// init: snap0 = bf16(concat(u,i)); embS = bf16(isq*emb) into gbuf
__global__ void k_init(const float* __restrict__ ue, const float* __restrict__ ie,
                       const float* __restrict__ isq,
                       unsigned* __restrict__ snap0, unsigned* __restrict__ gbuf) {
    int i = blockIdx.x * blockDim.x + threadIdx.x;
    const int n4 = NTOT * EDIM / 4;
    if (i < n4) {
        const int nu4 = NU * EDIM / 4;
        float4 v = (i < nu4) ? ((const float4*)ue)[i] : ((const float4*)ie)[i - nu4];
        float s = isq[i >> 4];
        uint2 b, bs;
        b.x = pack_bf2(v.x, v.y);
        b.y = pack_bf2(v.z, v.w);
        bs.x = pack_bf2(v.x * s, v.y * s);
        bs.y = pack_bf2(v.z * s, v.w * s);
        ((uint2*)snap0)[i] = b;
        ((uint2*)gbuf)[i] = bs;
    }
}

// zero the sentinel row NTOT of the two gather-input buffers
__global__ void k_zerorow(unsigned* __restrict__ a, unsigned* __restrict__ b) {
    int t = threadIdx.x;
    if (t < 32) {
        a[NTOT * 32 + t] = 0;
        b[NTOT * 32 + t] = 0;
    }
}

// ---------------- sparse gather (pull), bf16 rows, unweighted ----------------
// out[n] = sA[n] * sum_{m in nbr(n)} in[m].
// uint2 datapath: 16 lanes per row (lane sub = dims [4*sub,4*sub+4)), 4 rows
// per wave-load via neighbor groups g = lane>>4. Group g covers neighbors
// {tb*16 + 4t + g : t=0..3}:
//   g=0 -> {0,4,8,12}, g=1 -> {1,5,9,13}, g=2 -> {2,6,10,14}, g=3 -> {3,7,11,15}
// (disjoint union = the full 16-chunk; verified by enumeration). Each chunk
// issues 4 independent uint2 loads/group -> 16 rows in flight per wave.
// Sentinel zero-row at index NTOT pads lanes beyond the degree.
// NOTE: no readfirstlane on gw — R8's readfirstlane (scalar-load metadata)
// was the one diff vs the replay-stable R6 and the post-timing divergence
// suspect; gw is wave-uniform anyway.
__global__ __launch_bounds__(256) void k_gather(
    const unsigned* __restrict__ in_bf, unsigned* __restrict__ out_bf,
    const int* __restrict__ csr, const int* __restrict__ start,
    const int* __restrict__ deg, const float* __restrict__ sA) {
    int gw = (blockIdx.x * 256 + threadIdx.x) >> 6;   // global wave = row
    if (gw >= NTOT) return;
    int lane = threadIdx.x & 63;
    int sub = lane & 15;    // dim quad
    int g = lane >> 4;      // neighbor group 0..3
    int s0 = start[gw];
    int dg = deg[gw];
    float a0 = 0.f, a1 = 0.f, a2 = 0.f, a3 = 0.f;
    const uint2* in2 = (const uint2*)in_bf;
    for (int j0 = 0; j0 < dg; j0 += 64) {
        int lim = min(64, dg - j0);
        int nidx = NTOT;   // sentinel zero row
        if (lane < lim) nidx = csr[s0 + j0 + lane];
        for (int tb = 0; tb * 16 < lim; ++tb) {
            int m0 = __shfl(nidx, tb * 16 + 0 + g);
            int m1 = __shfl(nidx, tb * 16 + 4 + g);
            int m2 = __shfl(nidx, tb * 16 + 8 + g);
            int m3 = __shfl(nidx, tb * 16 + 12 + g);
            uint2 v0 = in2[m0 * 16 + sub];
            uint2 v1 = in2[m1 * 16 + sub];
            uint2 v2 = in2[m2 * 16 + sub];
            uint2 v3 = in2[m3 * 16 + sub];
            a0 += bf_lo(v0.x); a1 += bf_hi(v0.x); a2 += bf_lo(v0.y); a3 += bf_hi(v0.y);
            a0 += bf_lo(v1.x); a1 += bf_hi(v1.x); a2 += bf_lo(v1.y); a3 += bf_hi(v1.y);
            a0 += bf_lo(v2.x); a1 += bf_hi(v2.x); a2 += bf_lo(v2.y); a3 += bf_hi(v2.y);
            a0 += bf_lo(v3.x); a1 += bf_hi(v3.x); a2 += bf_lo(v3.y); a3 += bf_hi(v3.y);
        }
    }
    // reduce across the 4 neighbor groups (lane bits 4 and 5)
    a0 += __shfl_xor(a0, 16); a1 += __shfl_xor(a1, 16);
    a2 += __shfl_xor(a2, 16); a3 += __shfl_xor(a3, 16);
    a0 += __shfl_xor(a0, 32); a1 += __shfl_xor(a1, 32);
    a2 += __shfl_xor(a2, 32); a3 += __shfl_xor(a3, 32);
    if (lane < 16) {
        float s = sA[gw];
        uint2 o;
        o.x = pack_bf2(s * a0, s * a1);
        o.y = pack_bf2(s * a2, s * a3);
        ((uint2*)out_bf)[gw * 16 + sub] = o;
    }
}

// ---------------- dense per-row update via MFMA (all-bf16 state) ----------------
__global__ __launch_bounds__(256) void k_dense_mfma(
    const unsigned short* __restrict__ a_prev, unsigned* gbuf,
    unsigned short* __restrict__ snap_l, const float* __restrict__ isq,
    const unsigned short* __restrict__ wgb, const unsigned short* __restrict__ wbb,
    const float* __restrict__ bg, const float* __restrict__ bb, int writeScaled) {
    int lane = threadIdx.x & 63;
    int lanelo = lane & 15;
    int quad = lane >> 4;
    int wid = (blockIdx.x * blockDim.x + threadIdx.x) >> 6;
    if (wid >= NTILES) return;

    short8 bWg[4][2], bWb[4][2];
#pragma unroll
    for (int t = 0; t < 4; ++t) {
#pragma unroll
        for (int h = 0; h < 2; ++h) {
            int n = t * 16 + lanelo;
            int k0 = h * 32 + quad * 8;
            bWg[t][h] = *(const short8*)&wgb[n * 64 + k0];
            bWb[t][h] = *(const short8*)&wbb[n * 64 + k0];
        }
    }
    float bgv[4], bbv[4];
#pragma unroll
    for (int t = 0; t < 4; ++t) {
        bgv[t] = bg[t * 16 + lanelo];
        bbv[t] = bb[t * 16 + lanelo];
    }

    int rbase = wid * 16;
    int arow = rbase + lanelo;
    short8 aG[2], aAG[2];
#pragma unroll
    for (int h = 0; h < 2; ++h) {
        uint4 ug = *(const uint4*)(gbuf + arow * 32 + h * 16 + quad * 4);
        uint4 ua = *(const uint4*)((const unsigned*)a_prev + arow * 32 + h * 16 + quad * 4);
        aG[h] = *(const short8*)&ug;
        uint4 up;
        up.x = pack_bf2(bf_lo(ua.x) * bf_lo(ug.x), bf_hi(ua.x) * bf_hi(ug.x));
        up.y = pack_bf2(bf_lo(ua.y) * bf_lo(ug.y), bf_hi(ua.y) * bf_hi(ug.y));
        up.z = pack_bf2(bf_lo(ua.z) * bf_lo(ug.z), bf_hi(ua.z) * bf_hi(ug.z));
        up.w = pack_bf2(bf_lo(ua.w) * bf_lo(ug.w), bf_hi(ua.w) * bf_hi(ug.w));
        aAG[h] = *(const short8*)&up;
    }
    floatx4 accg[4], accb[4];
#pragma unroll
    for (int t = 0; t < 4; ++t) {
        accg[t] = (floatx4)(0.f);
        accb[t] = (floatx4)(0.f);
    }
#pragma unroll
    for (int t = 0; t < 4; ++t) {
#pragma unroll
        for (int h = 0; h < 2; ++h) {
            accg[t] = __builtin_amdgcn_mfma_f32_16x16x32_bf16(aG[h], bWg[t][h], accg[t], 0, 0, 0);
            accb[t] = __builtin_amdgcn_mfma_f32_16x16x32_bf16(aAG[h], bWb[t][h], accb[t], 0, 0, 0);
        }
    }
    float nv[4][4];
    float ss[4] = {0.f, 0.f, 0.f, 0.f};
#pragma unroll
    for (int i = 0; i < 4; ++i) {
        int r = rbase + quad * 4 + i;
#pragma unroll
        for (int t = 0; t < 4; ++t) {
            float a = __uint_as_float((unsigned)a_prev[r * 64 + t * 16 + lanelo] << 16);
            float e1 = accg[t][i] + bgv[t] + a;
            e1 = e1 >= 0.f ? e1 : 0.2f * e1;
            float e2 = accb[t][i] + bbv[t];
            e2 = e2 >= 0.f ? e2 : 0.2f * e2;
            float v = e1 + e2;
            nv[i][t] = v;
            ss[i] += v * v;
        }
    }
#pragma unroll
    for (int m = 1; m < 16; m <<= 1) {
#pragma unroll
        for (int i = 0; i < 4; ++i) ss[i] += __shfl_xor(ss[i], m, 64);
    }
#pragma unroll
    for (int i = 0; i < 4; ++i) {
        int r = rbase + quad * 4 + i;
        float rn = 1.0f / fmaxf(sqrtf(ss[i]), 1e-12f);
        float sc = isq[r] * rn;
#pragma unroll
        for (int t = 0; t < 4; ++t) {
            int idx = r * 64 + t * 16 + lanelo;
            float rr = nv[i][t] * rn;
            snap_l[idx] = f2bf(rr);
            if (writeScaled)
                ((unsigned short*)gbuf)[idx] = f2bf(nv[i][t] * sc);
        }
    }
}

// final mean: out = 0.25*(init_f32 + snap1 + snap2 + snap3)
__global__ void k_out(const float* __restrict__ ue, const float* __restrict__ ie,
                      const unsigned* __restrict__ s1, const unsigned* __restrict__ s2,
                      const unsigned* __restrict__ s3, float* __restrict__ out) {
    int i = blockIdx.x * blockDim.x + threadIdx.x;   // per 4 elems
    const int n4 = NTOT * EDIM / 4;
    if (i >= n4) return;
    const int nu4 = NU * EDIM / 4;
    float4 v = (i < nu4) ? ((const float4*)ue)[i] : ((const float4*)ie)[i - nu4];
    uint2 a = ((const uint2*)s1)[i];
    uint2 b = ((const uint2*)s2)[i];
    uint2 c = ((const uint2*)s3)[i];
    float4 o;
    o.x = 0.25f * (v.x + bf_lo(a.x) + bf_lo(b.x) + bf_lo(c.x));
    o.y = 0.25f * (v.y + bf_hi(a.x) + bf_hi(b.x) + bf_hi(c.x));
    o.z = 0.25f * (v.z + bf_lo(a.y) + bf_lo(b.y) + bf_lo(c.y));
    o.w = 0.25f * (v.w + bf_hi(a.y) + bf_hi(b.y) + bf_hi(c.y));
    ((float4*)out)[i] = o;
}

// ---------------- launch ----------------

extern "C" void kernel_launch(void* const* d_in, const int* in_sizes, int n_in,
                              void* d_out, int out_size, void* d_ws, size_t ws_size,
                              hipStream_t stream) {
    const float* u_emb = (const float*)d_in[0];
    const float* i_emb = (const float*)d_in[1];
    const float* Wgc = (const float*)d_in[2];
    const float* bgc = (const float*)d_in[3];
    const float* Wbi = (const float*)d_in[4];
    const float* bbi = (const float*)d_in[5];
    const int* edge_u = (const int*)d_in[6];
    const int* edge_i = (const int*)d_in[7];
    float* out = (float*)d_out;

    char* w = (char*)d_ws;
    auto alloc = [&](size_t bytes) {
        char* p = w;
        w += (bytes + 255) & ~(size_t)255;
        return p;
    };
    const size_t ROWBYTES = (size_t)(NTOT + 1) * EDIM * 2;   // +1 sentinel row
    int* deg = (int*)alloc((size_t)NTOT * 4);
    int* start = (int*)alloc((size_t)NTOT * 4);
    int* cursor = (int*)alloc((size_t)NTOT * 4);
    int* partials = (int*)alloc(256 * 4);
    int* csr = (int*)alloc((size_t)2 * NE * 4);
    float* isq = (float*)alloc((size_t)NTOT * 4);
    float* inv = (float*)alloc((size_t)NTOT * 4);
    unsigned short* wgb = (unsigned short*)alloc((size_t)NLAYERS * 4096 * 2);
    unsigned short* wbb = (unsigned short*)alloc((size_t)NLAYERS * 4096 * 2);
    unsigned* snap0 = (unsigned*)alloc((size_t)NTOT * EDIM * 2);
    unsigned* snap1 = (unsigned*)alloc((size_t)NTOT * EDIM * 2);
    unsigned* snap2 = (unsigned*)alloc((size_t)NTOT * EDIM * 2);
    unsigned* Ebuf = (unsigned*)alloc(ROWBYTES);    // = hpartial = snap3
    unsigned* gbuf = (unsigned*)alloc(ROWBYTES);    // = embS (in-place)
    unsigned* hpartial = Ebuf;                      // 19.2 MB fits; dead pre-init
    unsigned* snap3 = Ebuf;                         // written by dense L3

    // graph prep
    k_hist<<<NRANGE * NSLICE, 256, 0, stream>>>(edge_u, edge_i, hpartial);
    k_merge<<<(NWORDS + 255) / 256, 256, 0, stream>>>(hpartial, deg, isq, inv);
    k_blocksum<<<NBLK, 256, 0, stream>>>(deg, partials);
    k_scanpartials<<<1, 256, 0, stream>>>(partials, NBLK);
    k_scanfinal<<<NBLK, 256, 0, stream>>>(deg, partials, start, cursor);
    for (int p = 0; p < FILL_PASSES; ++p) {
        k_fill_pass<<<(NE + 255) / 256, 256, 0, stream>>>(
            edge_u, edge_i, cursor, csr, p * FILL_RANGE, (p + 1) * FILL_RANGE);
    }
    k_prepw<<<(NLAYERS * 4096 / 4 + 255) / 256, 256, 0, stream>>>(Wgc, Wbi, wgb, wbb);
    k_init<<<(NTOT * EDIM / 4 + 255) / 256, 256, 0, stream>>>(u_emb, i_emb, isq, snap0, gbuf);
    k_zerorow<<<1, 64, 0, stream>>>(Ebuf, gbuf);

    const int gatherBlocks = (NTOT * 64 + 255) / 256;   // one wave per row
    const int denseBlocks = (NTILES * 64 + 255) / 256;  // one wave per 16-row tile
    const unsigned short* aprev[3] = {(unsigned short*)snap0, (unsigned short*)snap1,
                                      (unsigned short*)snap2};
    unsigned short* snaps[3] = {(unsigned short*)snap1, (unsigned short*)snap2,
                                (unsigned short*)snap3};
    for (int l = 0; l < NLAYERS; ++l) {
        // E[n] = inv[n] * sum embS[m]      (embS = isq*emb, pre-scaled)
        k_gather<<<gatherBlocks, 256, 0, stream>>>(gbuf, Ebuf, csr, start, deg, inv);
        // g[n] = isq[n] * sum E[m]
        k_gather<<<gatherBlocks, 256, 0, stream>>>(Ebuf, gbuf, csr, start, deg, isq);
        k_dense_mfma<<<denseBlocks, 256, 0, stream>>>(
            aprev[l], gbuf, snaps[l], isq, wgb + (size_t)l * 4096, wbb + (size_t)l * 4096,
            bgc + (size_t)l * 64, bbi + (size_t)l * 64, l < NLAYERS - 1 ? 1 : 0);
    }
    k_out<<<(NTOT * EDIM / 4 + 255) / 256, 256, 0, stream>>>(
        u_emb, i_emb, snap1, snap2, snap3, out);
}